// Round 1
// baseline (1508.081 us; speedup 1.0000x reference)
//
#include <hip/hip_runtime.h>
#include <math.h>

// Problem constants (from setup_inputs)
constexpr int kB = 16;      // batch
constexpr int kD = 2048;    // rep dim
constexpr int kV = 504;     // verbs
constexpr int kR = 190;     // roles
constexpr int kH = 32;      // hidden
constexpr int kMR = 6;      // max roles/verb
constexpr int kG = 2000;    // group size
constexpr int kL = 3;       // attn layers
constexpr int kNH = 4;      // heads
constexpr int kHD = 8;      // head dim
constexpr int kC1 = kV + kR * kH;   // 6584 fused GEMM columns
constexpr int kNDS = 8;             // d-splits for k1a
constexpr int kDCH = kD / kNDS;     // 256

// ws layout (float offsets)
constexpr size_t WS_NODE = 0;                          // kB*kR*kH
constexpr size_t WS_X    = WS_NODE + (size_t)kB*kR*kH; // kV*kMR*kB*kH
constexpr size_t WS_PART = WS_X + (size_t)kV*kMR*kB*kH;// kNDS*kB*kC1

// out layout (float offsets), tuple concatenated flat
constexpr size_t O_VPOT = 0;                       // (B,V)
constexpr size_t O_NORM = O_VPOT + (size_t)kB*kV;  // (B,)
constexpr size_t O_VMAX = O_NORM + kB;             // (B,V)
constexpr size_t O_VRN  = O_VMAX + (size_t)kB*kV;  // (B,V,MR)
constexpr size_t O_VRM  = O_VRN + (size_t)kB*kV*kMR;
constexpr size_t O_VRI  = O_VRM + (size_t)kB*kV*kMR;

// ---------------- k1a: rep @ [W_v | W_r], d-split partials ----------------
__global__ __launch_bounds__(256) void k1a(const float* __restrict__ rep,
                                           const float* __restrict__ Wv,
                                           const float* __restrict__ Wr,
                                           float* __restrict__ part) {
  __shared__ float rl[kB][kDCH];
  const int tid = threadIdx.x;
  const int col = blockIdx.x * 256 + tid;
  const int d0 = blockIdx.y * kDCH;
  for (int i = tid; i < kB * kDCH; i += 256) {
    int b = i >> 8, dd = i & (kDCH - 1);
    rl[b][dd] = rep[b * kD + d0 + dd];
  }
  __syncthreads();
  if (col >= kC1) return;
  const float* Wp;
  int stride;
  if (col < kV) { Wp = Wv + (size_t)d0 * kV + col; stride = kV; }
  else          { Wp = Wr + (size_t)d0 * (kR*kH) + (col - kV); stride = kR*kH; }
  float acc[kB];
#pragma unroll
  for (int b = 0; b < kB; b++) acc[b] = 0.f;
  for (int dd = 0; dd < kDCH; dd++) {
    float w = Wp[(size_t)dd * stride];
#pragma unroll
    for (int b = 0; b < kB; b++) acc[b] += rl[b][dd] * w;
  }
  float* p = part + (size_t)(blockIdx.y * kB) * kC1 + col;
#pragma unroll
  for (int b = 0; b < kB; b++) p[(size_t)b * kC1] = acc[b];
}

// ---------------- k1b: reduce partials + bias, scatter to out/node -------
__global__ __launch_bounds__(256) void k1b(const float* __restrict__ part,
                                           const float* __restrict__ bv,
                                           const float* __restrict__ br,
                                           float* __restrict__ out,
                                           float* __restrict__ node) {
  int idx = blockIdx.x * 256 + threadIdx.x;
  if (idx >= kB * kC1) return;
  int b = idx / kC1, col = idx % kC1;
  float s = 0.f;
#pragma unroll
  for (int ds = 0; ds < kNDS; ds++) s += part[(size_t)(ds * kB + b) * kC1 + col];
  if (col < kV) out[O_VPOT + (size_t)b * kV + col] = s + bv[col];
  else          node[(size_t)b * (kR*kH) + (col - kV)] = s + br[col - kV];
}

// ---------------- k2: per-verb 3-layer MHA -------------------------------
__global__ __launch_bounds__(256) void k2(const float* __restrict__ node,
                                          const int* __restrict__ verb_roles,
                                          const float* __restrict__ in_w,
                                          const float* __restrict__ in_b,
                                          const float* __restrict__ out_w,
                                          const float* __restrict__ out_b,
                                          float* __restrict__ xout) {
  __shared__ float xs[kMR][kB][kH + 1];
  __shared__ float qkv[kMR][kB][3*kH + 1];
  __shared__ float ob[kMR][kB][kH + 1];
  __shared__ float wi[3*kH][kH + 1];
  __shared__ float bi[3*kH];
  __shared__ float wo[kH][kH + 1];
  __shared__ float bo[kH];
  __shared__ int roles[kMR];
  const int v = blockIdx.x;
  const int tid = threadIdx.x;
  if (tid < kMR) roles[tid] = verb_roles[v * kMR + tid];
  __syncthreads();
  // load x0 = node[b, r_s, :]
  for (int i = tid; i < kMR * kB * kH; i += 256) {
    int s = i / (kB * kH), rm = i % (kB * kH), b = rm / kH, h = rm % kH;
    int r = roles[s] < 0 ? 0 : roles[s];
    xs[s][b][h] = node[(size_t)b * (kR*kH) + r * kH + h];
  }
  for (int l = 0; l < kL; l++) {
    for (int i = tid; i < 3*kH*kH; i += 256) wi[i / kH][i % kH] = in_w[(size_t)l*3*kH*kH + i];
    for (int i = tid; i < kH*kH; i += 256)   wo[i / kH][i % kH] = out_w[(size_t)l*kH*kH + i];
    if (tid < 3*kH) bi[tid] = in_b[l*3*kH + tid];
    if (tid < kH)   bo[tid] = out_b[l*kH + tid];
    __syncthreads();
    // qkv[s][b][f] = x[s][b][:] . in_w[f][:] + in_b[f]
    for (int i = tid; i < kMR*kB*3*kH; i += 256) {
      int s = i / (kB*3*kH), rm = i % (kB*3*kH), b = rm / (3*kH), f = rm % (3*kH);
      float a = bi[f];
#pragma unroll
      for (int h = 0; h < kH; h++) a += xs[s][b][h] * wi[f][h];
      qkv[s][b][f] = a;
    }
    __syncthreads();
    // attention: one thread per (b, head)
    if (tid < kB * kNH) {
      const int b = tid & (kB - 1);
      const int hh = tid >> 4;
      const float scale = 0.35355339059327373f; // 1/sqrt(8)
      float sc[kMR][kMR];
      for (int s = 0; s < kMR; s++) {
        float q[kHD];
#pragma unroll
        for (int d = 0; d < kHD; d++) q[d] = qkv[s][b][hh*kHD + d] * scale;
        for (int t = 0; t < kMR; t++) {
          float a = 0.f;
#pragma unroll
          for (int d = 0; d < kHD; d++) a += q[d] * qkv[t][b][kH + hh*kHD + d];
          sc[s][t] = a;
        }
      }
      for (int s = 0; s < kMR; s++) {
        float m = -INFINITY;
        for (int t = 0; t < kMR; t++) if (roles[t] >= 0 && sc[s][t] > m) m = sc[s][t];
        float sum = 0.f;
        for (int t = 0; t < kMR; t++) {
          float e = (roles[t] >= 0) ? __expf(sc[s][t] - m) : 0.f;
          sc[s][t] = e; sum += e;
        }
        float inv = 1.f / sum;
        for (int t = 0; t < kMR; t++) sc[s][t] *= inv;
      }
      float o[kMR][kHD];
      for (int s = 0; s < kMR; s++)
#pragma unroll
        for (int d = 0; d < kHD; d++) o[s][d] = 0.f;
      for (int t = 0; t < kMR; t++) {
#pragma unroll
        for (int d = 0; d < kHD; d++) {
          float vv = qkv[t][b][2*kH + hh*kHD + d];
          for (int s = 0; s < kMR; s++) o[s][d] += sc[s][t] * vv;
        }
      }
      for (int s = 0; s < kMR; s++)
#pragma unroll
        for (int d = 0; d < kHD; d++) ob[s][b][hh*kHD + d] = o[s][d];
    }
    __syncthreads();
    // out projection -> xs
    for (int i = tid; i < kMR*kB*kH; i += 256) {
      int s = i / (kB*kH), rm = i % (kB*kH), b = rm / kH, f = rm % kH;
      float a = bo[f];
#pragma unroll
      for (int h = 0; h < kH; h++) a += ob[s][b][h] * wo[f][h];
      xs[s][b][f] = a;
    }
    __syncthreads();
  }
  for (int i = tid; i < kMR*kB*kH; i += 256) {
    int s = i / (kB*kH), rm = i % (kB*kH), b = rm / kH, h = rm % kH;
    xout[(((size_t)v*kMR + s)*kB + b)*kH + h] = xs[s][b][h];
  }
}

// ---------------- k3: logits + masked max/argmax/LSE per (v,s) -----------
__device__ inline void lse_merge(float& m, float& s, int& i, float om, float os, int oi) {
  if (om == -INFINITY) return;
  if (m == -INFINITY) { m = om; s = os; i = oi; return; }
  if (om > m)       { s = s * __expf(m - om) + os; m = om; i = oi; }
  else if (om < m)  { s = s + os * __expf(om - m); }
  else              { s += os; i = (oi < i) ? oi : i; }
}

__global__ __launch_bounds__(256) void k3(const float* __restrict__ xw,
                                          const int* __restrict__ verb_roles,
                                          const int* __restrict__ group_len,
                                          const float* __restrict__ Wn,
                                          const float* __restrict__ bn,
                                          float* __restrict__ out) {
  const int v = blockIdx.x, s = blockIdx.y;
  const int tid = threadIdx.x;
  const int r = verb_roles[v * kMR + s];
  if (r < 0) {
    if (tid < kB) {
      size_t o = ((size_t)tid * kV + v) * kMR + s;
      out[O_VRN + o] = 0.f; out[O_VRM + o] = 0.f; out[O_VRI + o] = 0.f;
    }
    return;
  }
  __shared__ float xs[kB][kH];
  for (int i = tid; i < kB * kH; i += 256)
    xs[i / kH][i % kH] = xw[((size_t)(v*kMR + s) * kB) * kH + i];
  __syncthreads();
  const int glen = group_len[r];
  const float* W = Wn + (size_t)r * kH * kG;
  const float* bb = bn + (size_t)r * kG;
  float m[kB], sum[kB]; int bi[kB];
#pragma unroll
  for (int b = 0; b < kB; b++) { m[b] = -INFINITY; sum[b] = 0.f; bi[b] = 0; }
  for (int g = tid; g < glen; g += 256) {
    float acc[kB];
    const float bg = bb[g];
#pragma unroll
    for (int b = 0; b < kB; b++) acc[b] = bg;
    for (int h = 0; h < kH; h++) {
      float w = W[(size_t)h * kG + g];
#pragma unroll
      for (int b = 0; b < kB; b++) acc[b] += xs[b][h] * w;
    }
#pragma unroll
    for (int b = 0; b < kB; b++) {
      float val = acc[b];
      float nm = fmaxf(m[b], val);
      sum[b] = sum[b] * __expf(m[b] - nm) + __expf(val - nm);
      bi[b] = (val > m[b]) ? g : bi[b];
      m[b] = nm;
    }
  }
  // 64-lane butterfly merge
#pragma unroll
  for (int off = 1; off < 64; off <<= 1) {
#pragma unroll
    for (int b = 0; b < kB; b++) {
      float om = __shfl_xor(m[b], off);
      float os = __shfl_xor(sum[b], off);
      int oi = __shfl_xor(bi[b], off);
      lse_merge(m[b], sum[b], bi[b], om, os, oi);
    }
  }
  __shared__ float rm[4][kB], rs[4][kB];
  __shared__ int ri[4][kB];
  const int wave = tid >> 6, lane = tid & 63;
  if (lane == 0) {
#pragma unroll
    for (int b = 0; b < kB; b++) { rm[wave][b] = m[b]; rs[wave][b] = sum[b]; ri[wave][b] = bi[b]; }
  }
  __syncthreads();
  if (tid < kB) {
    float M = rm[0][tid], S = rs[0][tid]; int I = ri[0][tid];
    for (int w = 1; w < 4; w++) lse_merge(M, S, I, rm[w][tid], rs[w][tid], ri[w][tid]);
    size_t o = ((size_t)tid * kV + v) * kMR + s;
    out[O_VRN + o] = M + logf(S);
    out[O_VRM + o] = M;
    out[O_VRI + o] = (float)I;
  }
}

// ---------------- k4: v_max, v_marginal LSE -> norm ----------------------
__global__ __launch_bounds__(256) void k4(float* __restrict__ out) {
  const int b = blockIdx.x;
  const int tid = threadIdx.x;
  float M = -INFINITY, S = 0.f;
  for (int v = tid; v < kV; v += 256) {
    float sm = 0.f, sx = 0.f;
#pragma unroll
    for (int s = 0; s < kMR; s++) {
      size_t o = ((size_t)b * kV + v) * kMR + s;
      sm += out[O_VRN + o];
      sx += out[O_VRM + o];
    }
    float vp = out[O_VPOT + (size_t)b * kV + v];
    float vm = sm + vp;
    out[O_VMAX + (size_t)b * kV + v] = sx + vp;
    float nm = fmaxf(M, vm);
    S = S * __expf(M - nm) + __expf(vm - nm);
    M = nm;
  }
#pragma unroll
  for (int off = 1; off < 64; off <<= 1) {
    float om = __shfl_xor(M, off);
    float os = __shfl_xor(S, off);
    if (om != -INFINITY) {
      if (M == -INFINITY) { M = om; S = os; }
      else if (om > M) { S = S * __expf(M - om) + os; M = om; }
      else { S += os * __expf(om - M); }
    }
  }
  __shared__ float rm2[4], rs2[4];
  const int wave = tid >> 6, lane = tid & 63;
  if (lane == 0) { rm2[wave] = M; rs2[wave] = S; }
  __syncthreads();
  if (tid == 0) {
    float Mm = rm2[0], Ss = rs2[0];
    for (int w = 1; w < 4; w++) {
      float om = rm2[w], os = rs2[w];
      if (om > Mm) { Ss = Ss * __expf(Mm - om) + os; Mm = om; }
      else { Ss += os * __expf(om - Mm); }
    }
    out[O_NORM + b] = Mm + logf(Ss);
  }
}

extern "C" void kernel_launch(void* const* d_in, const int* in_sizes, int n_in,
                              void* d_out, int out_size, void* d_ws, size_t ws_size,
                              hipStream_t stream) {
  const float* rep = (const float*)d_in[0];
  const float* Wv  = (const float*)d_in[1];
  const float* bv  = (const float*)d_in[2];
  const float* Wr  = (const float*)d_in[3];
  const float* br  = (const float*)d_in[4];
  const float* aiw = (const float*)d_in[5];
  const float* aib = (const float*)d_in[6];
  const float* aow = (const float*)d_in[7];
  const float* aob = (const float*)d_in[8];
  const float* Wn  = (const float*)d_in[9];
  const float* bnn = (const float*)d_in[10];
  const int* vrl   = (const int*)d_in[11];
  const int* gl    = (const int*)d_in[12];
  float* out = (float*)d_out;
  float* ws  = (float*)d_ws;

  k1a<<<dim3((kC1 + 255) / 256, kNDS), 256, 0, stream>>>(rep, Wv, Wr, ws + WS_PART);
  k1b<<<(kB * kC1 + 255) / 256, 256, 0, stream>>>(ws + WS_PART, bv, br, out, ws + WS_NODE);
  k2<<<kV, 256, 0, stream>>>(ws + WS_NODE, vrl, aiw, aib, aow, aob, ws + WS_X);
  k3<<<dim3(kV, kMR), 256, 0, stream>>>(ws + WS_X, vrl, gl, Wn, bnn, out);
  k4<<<kB, 256, 0, stream>>>(out);
}

// Round 2
// 558.527 us; speedup vs baseline: 2.7001x; 2.7001x over previous
//
#include <hip/hip_runtime.h>
#include <math.h>

// Problem constants (from setup_inputs)
constexpr int kB = 16;      // batch
constexpr int kD = 2048;    // rep dim
constexpr int kV = 504;     // verbs
constexpr int kR = 190;     // roles
constexpr int kH = 32;      // hidden
constexpr int kMR = 6;      // max roles/verb
constexpr int kG = 2000;    // group size
constexpr int kL = 3;       // attn layers
constexpr int kNH = 4;      // heads
constexpr int kHD = 8;      // head dim
constexpr int kC1 = kV + kR * kH;   // 6584 fused GEMM columns
constexpr int kNDS = 8;             // d-splits for k1a
constexpr int kDCH = kD / kNDS;     // 256

// k3 role-major params
constexpr int kMAXP = 64;   // max (v,s) pairs stored per role (mean 9.3, 64 ≈ 18 sigma)
constexpr int kGCH = 512;   // g-chunk length
constexpr int kGC = 4;      // number of g chunks (covers kG=2000)

// ws layout (float offsets).  REST is time-shared:
//   phase 1 (k1a/k1b): PART partials (kNDS*kB*kC1 = 842752 floats)
//   phase 2 (k0/k3a/k3b): PM/PS/PI partials + role lists (592958 floats)
// Safe because the stream serializes k1b before k0/k3a.
constexpr size_t WS_NODE = 0;                           // kB*kR*kH      = 97280
constexpr size_t WS_X    = WS_NODE + (size_t)kB*kR*kH;  // kV*kMR*kB*kH  = 1548288
constexpr size_t WS_REST = WS_X + (size_t)kV*kMR*kB*kH; // max(...)      = 842752
constexpr size_t WS_PART = WS_REST;
constexpr size_t WS_PM   = WS_REST;                               // kV*kMR*kB*kGC
constexpr size_t WS_PS   = WS_PM + (size_t)kV*kMR*kB*kGC;
constexpr size_t WS_PI   = WS_PS + (size_t)kV*kMR*kB*kGC;
constexpr size_t WS_CNT  = WS_PI + (size_t)kV*kMR*kB*kGC;         // kR ints
constexpr size_t WS_PAIR = WS_CNT + kR;                           // kR*kMAXP ints

// out layout (float offsets), tuple concatenated flat
constexpr size_t O_VPOT = 0;                       // (B,V)
constexpr size_t O_NORM = O_VPOT + (size_t)kB*kV;  // (B,)
constexpr size_t O_VMAX = O_NORM + kB;             // (B,V)
constexpr size_t O_VRN  = O_VMAX + (size_t)kB*kV;  // (B,V,MR)
constexpr size_t O_VRM  = O_VRN + (size_t)kB*kV*kMR;
constexpr size_t O_VRI  = O_VRM + (size_t)kB*kV*kMR;

// ---------------- k1a: rep @ [W_v | W_r], d-split partials ----------------
__global__ __launch_bounds__(256) void k1a(const float* __restrict__ rep,
                                           const float* __restrict__ Wv,
                                           const float* __restrict__ Wr,
                                           float* __restrict__ part) {
  __shared__ float rl[kB][kDCH];
  const int tid = threadIdx.x;
  const int col = blockIdx.x * 256 + tid;
  const int d0 = blockIdx.y * kDCH;
  for (int i = tid; i < kB * kDCH; i += 256) {
    int b = i >> 8, dd = i & (kDCH - 1);
    rl[b][dd] = rep[b * kD + d0 + dd];
  }
  __syncthreads();
  if (col >= kC1) return;
  const float* Wp;
  int stride;
  if (col < kV) { Wp = Wv + (size_t)d0 * kV + col; stride = kV; }
  else          { Wp = Wr + (size_t)d0 * (kR*kH) + (col - kV); stride = kR*kH; }
  float acc[kB];
#pragma unroll
  for (int b = 0; b < kB; b++) acc[b] = 0.f;
  for (int dd = 0; dd < kDCH; dd++) {
    float w = Wp[(size_t)dd * stride];
#pragma unroll
    for (int b = 0; b < kB; b++) acc[b] += rl[b][dd] * w;
  }
  float* p = part + (size_t)(blockIdx.y * kB) * kC1 + col;
#pragma unroll
  for (int b = 0; b < kB; b++) p[(size_t)b * kC1] = acc[b];
}

// ---------------- k1b: reduce partials + bias, scatter to out/node -------
__global__ __launch_bounds__(256) void k1b(const float* __restrict__ part,
                                           const float* __restrict__ bv,
                                           const float* __restrict__ br,
                                           float* __restrict__ out,
                                           float* __restrict__ node) {
  int idx = blockIdx.x * 256 + threadIdx.x;
  if (idx >= kB * kC1) return;
  int b = idx / kC1, col = idx % kC1;
  float s = 0.f;
#pragma unroll
  for (int ds = 0; ds < kNDS; ds++) s += part[(size_t)(ds * kB + b) * kC1 + col];
  if (col < kV) out[O_VPOT + (size_t)b * kV + col] = s + bv[col];
  else          node[(size_t)b * (kR*kH) + (col - kV)] = s + br[col - kV];
}

// ---------------- k0: build role -> pair lists ---------------------------
__global__ __launch_bounds__(256) void k0(const int* __restrict__ verb_roles,
                                          int* __restrict__ cnt,
                                          int* __restrict__ pairs) {
  const int tid = threadIdx.x;
  for (int i = tid; i < kR; i += 256) cnt[i] = 0;
  __syncthreads();
  for (int i = tid; i < kV * kMR; i += 256) {
    int r = verb_roles[i];
    if (r >= 0) {
      int pos = atomicAdd(&cnt[r], 1);
      if (pos < kMAXP) pairs[r * kMAXP + pos] = i;   // i = v*kMR + s
    }
  }
}

// ---------------- k2: per-verb 3-layer MHA -------------------------------
__global__ __launch_bounds__(256) void k2(const float* __restrict__ node,
                                          const int* __restrict__ verb_roles,
                                          const float* __restrict__ in_w,
                                          const float* __restrict__ in_b,
                                          const float* __restrict__ out_w,
                                          const float* __restrict__ out_b,
                                          float* __restrict__ xout) {
  __shared__ float xs[kMR][kB][kH + 1];
  __shared__ float qkv[kMR][kB][3*kH + 1];
  __shared__ float ob[kMR][kB][kH + 1];
  __shared__ float wi[3*kH][kH + 1];
  __shared__ float bi[3*kH];
  __shared__ float wo[kH][kH + 1];
  __shared__ float bo[kH];
  __shared__ int roles[kMR];
  const int v = blockIdx.x;
  const int tid = threadIdx.x;
  if (tid < kMR) roles[tid] = verb_roles[v * kMR + tid];
  __syncthreads();
  for (int i = tid; i < kMR * kB * kH; i += 256) {
    int s = i / (kB * kH), rm = i % (kB * kH), b = rm / kH, h = rm % kH;
    int r = roles[s] < 0 ? 0 : roles[s];
    xs[s][b][h] = node[(size_t)b * (kR*kH) + r * kH + h];
  }
  for (int l = 0; l < kL; l++) {
    for (int i = tid; i < 3*kH*kH; i += 256) wi[i / kH][i % kH] = in_w[(size_t)l*3*kH*kH + i];
    for (int i = tid; i < kH*kH; i += 256)   wo[i / kH][i % kH] = out_w[(size_t)l*kH*kH + i];
    if (tid < 3*kH) bi[tid] = in_b[l*3*kH + tid];
    if (tid < kH)   bo[tid] = out_b[l*kH + tid];
    __syncthreads();
    for (int i = tid; i < kMR*kB*3*kH; i += 256) {
      int s = i / (kB*3*kH), rm = i % (kB*3*kH), b = rm / (3*kH), f = rm % (3*kH);
      float a = bi[f];
#pragma unroll
      for (int h = 0; h < kH; h++) a += xs[s][b][h] * wi[f][h];
      qkv[s][b][f] = a;
    }
    __syncthreads();
    if (tid < kB * kNH) {
      const int b = tid & (kB - 1);
      const int hh = tid >> 4;
      const float scale = 0.35355339059327373f; // 1/sqrt(8)
      float sc[kMR][kMR];
      for (int s = 0; s < kMR; s++) {
        float q[kHD];
#pragma unroll
        for (int d = 0; d < kHD; d++) q[d] = qkv[s][b][hh*kHD + d] * scale;
        for (int t = 0; t < kMR; t++) {
          float a = 0.f;
#pragma unroll
          for (int d = 0; d < kHD; d++) a += q[d] * qkv[t][b][kH + hh*kHD + d];
          sc[s][t] = a;
        }
      }
      for (int s = 0; s < kMR; s++) {
        float m = -INFINITY;
        for (int t = 0; t < kMR; t++) if (roles[t] >= 0 && sc[s][t] > m) m = sc[s][t];
        float sum = 0.f;
        for (int t = 0; t < kMR; t++) {
          float e = (roles[t] >= 0) ? __expf(sc[s][t] - m) : 0.f;
          sc[s][t] = e; sum += e;
        }
        float inv = 1.f / sum;
        for (int t = 0; t < kMR; t++) sc[s][t] *= inv;
      }
      float o[kMR][kHD];
      for (int s = 0; s < kMR; s++)
#pragma unroll
        for (int d = 0; d < kHD; d++) o[s][d] = 0.f;
      for (int t = 0; t < kMR; t++) {
#pragma unroll
        for (int d = 0; d < kHD; d++) {
          float vv = qkv[t][b][2*kH + hh*kHD + d];
          for (int s = 0; s < kMR; s++) o[s][d] += sc[s][t] * vv;
        }
      }
      for (int s = 0; s < kMR; s++)
#pragma unroll
        for (int d = 0; d < kHD; d++) ob[s][b][hh*kHD + d] = o[s][d];
    }
    __syncthreads();
    for (int i = tid; i < kMR*kB*kH; i += 256) {
      int s = i / (kB*kH), rm = i % (kB*kH), b = rm / kH, f = rm % kH;
      float a = bo[f];
#pragma unroll
      for (int h = 0; h < kH; h++) a += ob[s][b][h] * wo[f][h];
      xs[s][b][f] = a;
    }
    __syncthreads();
  }
  for (int i = tid; i < kMR*kB*kH; i += 256) {
    int s = i / (kB*kH), rm = i % (kB*kH), b = rm / kH, h = rm % kH;
    xout[(((size_t)v*kMR + s)*kB + b)*kH + h] = xs[s][b][h];
  }
}

// ---------------- k3a: role-major logits, per-thread online softmax ------
// block = (role r, g-chunk gc); 512 threads = 8 waves x (4 pairs x 16 b).
// Thread owns one (pair, b): x row in 32 VGPRs, W/bias loads wave-uniform
// (g is a uniform loop var) -> compiler emits scalar loads; online state is
// 3 registers. No LDS, no cross-thread reduction.
__global__ __launch_bounds__(512) void k3a(const float* __restrict__ xw,
                                           const int* __restrict__ cnt,
                                           const int* __restrict__ pairs,
                                           const int* __restrict__ group_len,
                                           const float* __restrict__ Wn,
                                           const float* __restrict__ bn,
                                           float* __restrict__ PM,
                                           float* __restrict__ PS,
                                           float* __restrict__ PI) {
  const int r = blockIdx.x;
  const int gc = blockIdx.y;
  int c = cnt[r]; if (c > kMAXP) c = kMAXP;
  if (c == 0) return;
  const int glen = group_len[r];
  const int g0 = gc * kGCH;
  if (g0 >= glen) return;
  const int gend = (g0 + kGCH < glen) ? g0 + kGCH : glen;
  const int tid = threadIdx.x;
  const int wave = tid >> 6, lane = tid & 63;
  const int b = tid & 15;
  const float* W = Wn + (size_t)r * kH * kG;
  const float* bias = bn + (size_t)r * kG;
  for (int p = wave * 4 + (lane >> 4); p < c; p += 32) {
    const int pr = pairs[r * kMAXP + p];
    float x[kH];
    const float4* xp = (const float4*)(xw + ((size_t)pr * kB + b) * kH);
#pragma unroll
    for (int j = 0; j < kH / 4; j++) {
      float4 t = xp[j];
      x[4*j] = t.x; x[4*j+1] = t.y; x[4*j+2] = t.z; x[4*j+3] = t.w;
    }
    float m = -INFINITY, s = 0.f; int bi = 0;
    for (int g = g0; g < gend; g++) {
      float acc = bias[g];
#pragma unroll
      for (int h = 0; h < kH; h++) acc += x[h] * W[(size_t)h * kG + g];
      float d = acc - m;
      if (d > 0.f) { s = s * __expf(-d) + 1.f; m = acc; bi = g; }
      else         { s += __expf(d); }
    }
    size_t o = ((size_t)pr * kB + b) * kGC + gc;
    PM[o] = m; PS[o] = s; PI[o] = (float)bi;
  }
}

// ---------------- k3b: merge g-chunk partials -> outputs -----------------
__device__ inline void lse_merge(float& m, float& s, int& i, float om, float os, int oi) {
  if (om == -INFINITY) return;
  if (m == -INFINITY) { m = om; s = os; i = oi; return; }
  if (om > m)       { s = s * __expf(m - om) + os; m = om; i = oi; }
  else if (om < m)  { s = s + os * __expf(om - m); }
  else              { s += os; i = (oi < i) ? oi : i; }
}

__global__ __launch_bounds__(256) void k3b(const int* __restrict__ verb_roles,
                                           const int* __restrict__ group_len,
                                           const float* __restrict__ PM,
                                           const float* __restrict__ PS,
                                           const float* __restrict__ PI,
                                           float* __restrict__ out) {
  const int idx = blockIdx.x * 256 + threadIdx.x;
  if (idx >= kV * kMR * kB) return;
  const int pr = idx >> 4;        // v*kMR + s
  const int b = idx & 15;
  const int v = pr / kMR, s = pr % kMR;
  const size_t o = ((size_t)b * kV + v) * kMR + s;
  const int r = verb_roles[pr];
  if (r < 0) {
    out[O_VRN + o] = 0.f; out[O_VRM + o] = 0.f; out[O_VRI + o] = 0.f;
    return;
  }
  const int glen = group_len[r];
  const int ngc = (glen + kGCH - 1) / kGCH;
  float M = -INFINITY, S = 0.f; int I = 0;
  for (int gc = 0; gc < ngc; gc++) {
    size_t po = ((size_t)pr * kB + b) * kGC + gc;
    lse_merge(M, S, I, PM[po], PS[po], (int)PI[po]);
  }
  out[O_VRN + o] = M + logf(S);
  out[O_VRM + o] = M;
  out[O_VRI + o] = (float)I;
}

// ---------------- k4: v_max, v_marginal LSE -> norm ----------------------
__global__ __launch_bounds__(256) void k4(float* __restrict__ out) {
  const int b = blockIdx.x;
  const int tid = threadIdx.x;
  float M = -INFINITY, S = 0.f;
  for (int v = tid; v < kV; v += 256) {
    float sm = 0.f, sx = 0.f;
#pragma unroll
    for (int s = 0; s < kMR; s++) {
      size_t o = ((size_t)b * kV + v) * kMR + s;
      sm += out[O_VRN + o];
      sx += out[O_VRM + o];
    }
    float vp = out[O_VPOT + (size_t)b * kV + v];
    float vm = sm + vp;
    out[O_VMAX + (size_t)b * kV + v] = sx + vp;
    float nm = fmaxf(M, vm);
    S = S * __expf(M - nm) + __expf(vm - nm);
    M = nm;
  }
#pragma unroll
  for (int off = 1; off < 64; off <<= 1) {
    float om = __shfl_xor(M, off);
    float os = __shfl_xor(S, off);
    if (om != -INFINITY) {
      if (M == -INFINITY) { M = om; S = os; }
      else if (om > M) { S = S * __expf(M - om) + os; M = om; }
      else { S += os * __expf(om - M); }
    }
  }
  __shared__ float rm2[4], rs2[4];
  const int wave = tid >> 6, lane = tid & 63;
  if (lane == 0) { rm2[wave] = M; rs2[wave] = S; }
  __syncthreads();
  if (tid == 0) {
    float Mm = rm2[0], Ss = rs2[0];
    for (int w = 1; w < 4; w++) {
      float om = rm2[w], os = rs2[w];
      if (om > Mm) { Ss = Ss * __expf(Mm - om) + os; Mm = om; }
      else { Ss += os * __expf(om - Mm); }
    }
    out[O_NORM + b] = Mm + logf(Ss);
  }
}

extern "C" void kernel_launch(void* const* d_in, const int* in_sizes, int n_in,
                              void* d_out, int out_size, void* d_ws, size_t ws_size,
                              hipStream_t stream) {
  const float* rep = (const float*)d_in[0];
  const float* Wv  = (const float*)d_in[1];
  const float* bv  = (const float*)d_in[2];
  const float* Wr  = (const float*)d_in[3];
  const float* br  = (const float*)d_in[4];
  const float* aiw = (const float*)d_in[5];
  const float* aib = (const float*)d_in[6];
  const float* aow = (const float*)d_in[7];
  const float* aob = (const float*)d_in[8];
  const float* Wn  = (const float*)d_in[9];
  const float* bnn = (const float*)d_in[10];
  const int* vrl   = (const int*)d_in[11];
  const int* gl    = (const int*)d_in[12];
  float* out = (float*)d_out;
  float* ws  = (float*)d_ws;
  int* icnt  = (int*)(ws + WS_CNT);
  int* ipair = (int*)(ws + WS_PAIR);

  k1a<<<dim3((kC1 + 255) / 256, kNDS), 256, 0, stream>>>(rep, Wv, Wr, ws + WS_PART);
  k1b<<<(kB * kC1 + 255) / 256, 256, 0, stream>>>(ws + WS_PART, bv, br, out, ws + WS_NODE);
  k0<<<1, 256, 0, stream>>>(vrl, icnt, ipair);
  k2<<<kV, 256, 0, stream>>>(ws + WS_NODE, vrl, aiw, aib, aow, aob, ws + WS_X);
  k3a<<<dim3(kR, kGC), 512, 0, stream>>>(ws + WS_X, icnt, ipair, gl, Wn, bnn,
                                         ws + WS_PM, ws + WS_PS, ws + WS_PI);
  k3b<<<(kV * kMR * kB + 255) / 256, 256, 0, stream>>>(vrl, gl, ws + WS_PM, ws + WS_PS,
                                                       ws + WS_PI, out);
  k4<<<kB, 256, 0, stream>>>(out);
}

// Round 3
// 353.426 us; speedup vs baseline: 4.2670x; 1.5803x over previous
//
#include <hip/hip_runtime.h>
#include <math.h>

// Problem constants (from setup_inputs)
constexpr int kB = 16;      // batch
constexpr int kD = 2048;    // rep dim
constexpr int kV = 504;     // verbs
constexpr int kR = 190;     // roles
constexpr int kH = 32;      // hidden
constexpr int kMR = 6;      // max roles/verb
constexpr int kG = 2000;    // group size
constexpr int kL = 3;       // attn layers
constexpr int kNH = 4;      // heads
constexpr int kHD = 8;      // head dim
constexpr int kC1 = kV + kR * kH;   // 6584 fused GEMM columns
constexpr int kNDS = 8;             // d-splits for k1a
constexpr int kDCH = kD / kNDS;     // 256

// k3 role-major params
constexpr int kMAXP = 64;   // max (v,s) pairs stored per role (mean 9.3)
constexpr int kGCH = 512;   // g-chunk length
constexpr int kGC = 4;      // number of g chunks (covers kG=2000)

// ws layout (float offsets).  REST is time-shared:
//   phase 1 (k1a/k1b): PART partials (kNDS*kB*kC1 = 842752 floats)
//   phase 2 (k0/k3a/k3b): PM/PS/PI partials + role lists (~593K floats)
constexpr size_t WS_NODE = 0;                           // kB*kR*kH      = 97280
constexpr size_t WS_X    = WS_NODE + (size_t)kB*kR*kH;  // kV*kMR*kB*kH  = 1548288
constexpr size_t WS_REST = WS_X + (size_t)kV*kMR*kB*kH;
constexpr size_t WS_PART = WS_REST;
constexpr size_t WS_PM   = WS_REST;                               // kV*kMR*kB*kGC
constexpr size_t WS_PS   = WS_PM + (size_t)kV*kMR*kB*kGC;
constexpr size_t WS_PI   = WS_PS + (size_t)kV*kMR*kB*kGC;
constexpr size_t WS_CNT  = WS_PI + (size_t)kV*kMR*kB*kGC;         // kR ints
constexpr size_t WS_PAIR = WS_CNT + kR;                           // kR*kMAXP ints

// out layout (float offsets), tuple concatenated flat
constexpr size_t O_VPOT = 0;                       // (B,V)
constexpr size_t O_NORM = O_VPOT + (size_t)kB*kV;  // (B,)
constexpr size_t O_VMAX = O_NORM + kB;             // (B,V)
constexpr size_t O_VRN  = O_VMAX + (size_t)kB*kV;  // (B,V,MR)
constexpr size_t O_VRM  = O_VRN + (size_t)kB*kV*kMR;
constexpr size_t O_VRI  = O_VRM + (size_t)kB*kV*kMR;

// ---------------- k1a: rep @ [W_v | W_r], d-split partials ----------------
__global__ __launch_bounds__(256) void k1a(const float* __restrict__ rep,
                                           const float* __restrict__ Wv,
                                           const float* __restrict__ Wr,
                                           float* __restrict__ part) {
  __shared__ float rl[kB][kDCH];
  const int tid = threadIdx.x;
  const int col = blockIdx.x * 256 + tid;
  const int d0 = blockIdx.y * kDCH;
  for (int i = tid; i < kB * kDCH; i += 256) {
    int b = i >> 8, dd = i & (kDCH - 1);
    rl[b][dd] = rep[b * kD + d0 + dd];
  }
  __syncthreads();
  if (col >= kC1) return;
  const float* Wp;
  int stride;
  if (col < kV) { Wp = Wv + (size_t)d0 * kV + col; stride = kV; }
  else          { Wp = Wr + (size_t)d0 * (kR*kH) + (col - kV); stride = kR*kH; }
  float acc[kB];
#pragma unroll
  for (int b = 0; b < kB; b++) acc[b] = 0.f;
  for (int dd = 0; dd < kDCH; dd++) {
    float w = Wp[(size_t)dd * stride];
#pragma unroll
    for (int b = 0; b < kB; b++) acc[b] += rl[b][dd] * w;
  }
  float* p = part + (size_t)(blockIdx.y * kB) * kC1 + col;
#pragma unroll
  for (int b = 0; b < kB; b++) p[(size_t)b * kC1] = acc[b];
}

// ---------------- k1b: reduce partials + bias, scatter to out/node -------
__global__ __launch_bounds__(256) void k1b(const float* __restrict__ part,
                                           const float* __restrict__ bv,
                                           const float* __restrict__ br,
                                           float* __restrict__ out,
                                           float* __restrict__ node) {
  int idx = blockIdx.x * 256 + threadIdx.x;
  if (idx >= kB * kC1) return;
  int b = idx / kC1, col = idx % kC1;
  float s = 0.f;
#pragma unroll
  for (int ds = 0; ds < kNDS; ds++) s += part[(size_t)(ds * kB + b) * kC1 + col];
  if (col < kV) out[O_VPOT + (size_t)b * kV + col] = s + bv[col];
  else          node[(size_t)b * (kR*kH) + (col - kV)] = s + br[col - kV];
}

// ---------------- k0: build role -> pair lists ---------------------------
__global__ __launch_bounds__(256) void k0(const int* __restrict__ verb_roles,
                                          int* __restrict__ cnt,
                                          int* __restrict__ pairs) {
  const int tid = threadIdx.x;
  for (int i = tid; i < kR; i += 256) cnt[i] = 0;
  __syncthreads();
  for (int i = tid; i < kV * kMR; i += 256) {
    int r = verb_roles[i];
    if (r >= 0) {
      int pos = atomicAdd(&cnt[r], 1);
      if (pos < kMAXP) pairs[r * kMAXP + pos] = i;   // i = v*kMR + s
    }
  }
}

// ---------------- k2: per-verb 3-layer MHA -------------------------------
__global__ __launch_bounds__(256) void k2(const float* __restrict__ node,
                                          const int* __restrict__ verb_roles,
                                          const float* __restrict__ in_w,
                                          const float* __restrict__ in_b,
                                          const float* __restrict__ out_w,
                                          const float* __restrict__ out_b,
                                          float* __restrict__ xout) {
  __shared__ float xs[kMR][kB][kH + 1];
  __shared__ float qkv[kMR][kB][3*kH + 1];
  __shared__ float ob[kMR][kB][kH + 1];
  __shared__ float wi[3*kH][kH + 1];
  __shared__ float bi[3*kH];
  __shared__ float wo[kH][kH + 1];
  __shared__ float bo[kH];
  __shared__ int roles[kMR];
  const int v = blockIdx.x;
  const int tid = threadIdx.x;
  if (tid < kMR) roles[tid] = verb_roles[v * kMR + tid];
  __syncthreads();
  for (int i = tid; i < kMR * kB * kH; i += 256) {
    int s = i / (kB * kH), rm = i % (kB * kH), b = rm / kH, h = rm % kH;
    int r = roles[s] < 0 ? 0 : roles[s];
    xs[s][b][h] = node[(size_t)b * (kR*kH) + r * kH + h];
  }
  for (int l = 0; l < kL; l++) {
    for (int i = tid; i < 3*kH*kH; i += 256) wi[i / kH][i % kH] = in_w[(size_t)l*3*kH*kH + i];
    for (int i = tid; i < kH*kH; i += 256)   wo[i / kH][i % kH] = out_w[(size_t)l*kH*kH + i];
    if (tid < 3*kH) bi[tid] = in_b[l*3*kH + tid];
    if (tid < kH)   bo[tid] = out_b[l*kH + tid];
    __syncthreads();
    for (int i = tid; i < kMR*kB*3*kH; i += 256) {
      int s = i / (kB*3*kH), rm = i % (kB*3*kH), b = rm / (3*kH), f = rm % (3*kH);
      float a = bi[f];
#pragma unroll
      for (int h = 0; h < kH; h++) a += xs[s][b][h] * wi[f][h];
      qkv[s][b][f] = a;
    }
    __syncthreads();
    if (tid < kB * kNH) {
      const int b = tid & (kB - 1);
      const int hh = tid >> 4;
      const float scale = 0.35355339059327373f; // 1/sqrt(8)
      float sc[kMR][kMR];
      for (int s = 0; s < kMR; s++) {
        float q[kHD];
#pragma unroll
        for (int d = 0; d < kHD; d++) q[d] = qkv[s][b][hh*kHD + d] * scale;
        for (int t = 0; t < kMR; t++) {
          float a = 0.f;
#pragma unroll
          for (int d = 0; d < kHD; d++) a += q[d] * qkv[t][b][kH + hh*kHD + d];
          sc[s][t] = a;
        }
      }
      for (int s = 0; s < kMR; s++) {
        float m = -INFINITY;
        for (int t = 0; t < kMR; t++) if (roles[t] >= 0 && sc[s][t] > m) m = sc[s][t];
        float sum = 0.f;
        for (int t = 0; t < kMR; t++) {
          float e = (roles[t] >= 0) ? __expf(sc[s][t] - m) : 0.f;
          sc[s][t] = e; sum += e;
        }
        float inv = 1.f / sum;
        for (int t = 0; t < kMR; t++) sc[s][t] *= inv;
      }
      float o[kMR][kHD];
      for (int s = 0; s < kMR; s++)
#pragma unroll
        for (int d = 0; d < kHD; d++) o[s][d] = 0.f;
      for (int t = 0; t < kMR; t++) {
#pragma unroll
        for (int d = 0; d < kHD; d++) {
          float vv = qkv[t][b][2*kH + hh*kHD + d];
          for (int s = 0; s < kMR; s++) o[s][d] += sc[s][t] * vv;
        }
      }
      for (int s = 0; s < kMR; s++)
#pragma unroll
        for (int d = 0; d < kHD; d++) ob[s][b][hh*kHD + d] = o[s][d];
    }
    __syncthreads();
    for (int i = tid; i < kMR*kB*kH; i += 256) {
      int s = i / (kB*kH), rm = i % (kB*kH), b = rm / kH, f = rm % kH;
      float a = bo[f];
#pragma unroll
      for (int h = 0; h < kH; h++) a += ob[s][b][h] * wo[f][h];
      xs[s][b][f] = a;
    }
    __syncthreads();
  }
  for (int i = tid; i < kMR*kB*kH; i += 256) {
    int s = i / (kB*kH), rm = i % (kB*kH), b = rm / kH, h = rm % kH;
    xout[(((size_t)v*kMR + s)*kB + b)*kH + h] = xs[s][b][h];
  }
}

// ---------------- k3a: role-major logits, LDS-staged W -------------------
// block = (role r, g-chunk gc); 512 threads = 8 waves x (4 pairs x 16 b).
// W chunk staged transposed into LDS as [g][36] float rows (16B-aligned ->
// uniform ds_read_b128 broadcast per g; staging writes 8-way conflicted but
// only 32 instr/thread). 4 partial accumulators break the 32-deep FMA chain.
__global__ __launch_bounds__(512) void k3a(const float* __restrict__ xw,
                                           const int* __restrict__ cnt,
                                           const int* __restrict__ pairs,
                                           const int* __restrict__ group_len,
                                           const float* __restrict__ Wn,
                                           const float* __restrict__ bn,
                                           float* __restrict__ PM,
                                           float* __restrict__ PS,
                                           float* __restrict__ PI) {
  __shared__ float4 Wl[kGCH][9];   // [g][0..7]=W row, [8].x=bias
  const int r = blockIdx.x;
  const int gc = blockIdx.y;
  const int glen = group_len[r];
  const int g0 = gc * kGCH;
  if (g0 >= glen) return;
  int c = cnt[r]; if (c > kMAXP) c = kMAXP;
  if (c == 0) return;
  const int gn = (g0 + kGCH < glen) ? kGCH : (glen - g0);
  const int tid = threadIdx.x;
  const float* W = Wn + (size_t)r * kH * kG + g0;
  const float* bias = bn + (size_t)r * kG + g0;
  // stage: coalesced global reads (consecutive g per lane)
  for (int g = tid; g < gn; g += 512) {
    float* row = (float*)&Wl[g][0];
#pragma unroll
    for (int h = 0; h < kH; h++) row[h] = W[(size_t)h * kG + g];
    row[kH] = bias[g];
  }
  __syncthreads();
  const int wave = tid >> 6, lane = tid & 63;
  const int b = tid & 15;
  for (int p = wave * 4 + (lane >> 4); p < c; p += 32) {
    const int pr = pairs[r * kMAXP + p];
    float4 x[8];
    const float4* xp = (const float4*)(xw + ((size_t)pr * kB + b) * kH);
#pragma unroll
    for (int j = 0; j < 8; j++) x[j] = xp[j];
    float m = -INFINITY, s = 0.f; int bi = 0;
    for (int g = 0; g < gn; g++) {
      const float4* w = &Wl[g][0];
      float a0 = 0.f, a1 = 0.f, a2 = 0.f, a3 = 0.f;
#pragma unroll
      for (int j = 0; j < 8; j += 4) {
        float4 w0 = w[j], w1 = w[j+1], w2 = w[j+2], w3 = w[j+3];
        a0 = fmaf(x[j].x, w0.x, fmaf(x[j].y, w0.y, fmaf(x[j].z, w0.z, fmaf(x[j].w, w0.w, a0))));
        a1 = fmaf(x[j+1].x, w1.x, fmaf(x[j+1].y, w1.y, fmaf(x[j+1].z, w1.z, fmaf(x[j+1].w, w1.w, a1))));
        a2 = fmaf(x[j+2].x, w2.x, fmaf(x[j+2].y, w2.y, fmaf(x[j+2].z, w2.z, fmaf(x[j+2].w, w2.w, a2))));
        a3 = fmaf(x[j+3].x, w3.x, fmaf(x[j+3].y, w3.y, fmaf(x[j+3].z, w3.z, fmaf(x[j+3].w, w3.w, a3))));
      }
      float acc = ((a0 + a1) + (a2 + a3)) + w[8].x;
      float d = acc - m;
      bool gt = d > 0.f;
      float e = __expf(gt ? -d : d);   // first iter: exp(-inf) = 0
      s = gt ? fmaf(s, e, 1.f) : s + e;
      bi = gt ? g0 + g : bi;
      m = gt ? acc : m;
    }
    size_t o = ((size_t)pr * kB + b) * kGC + gc;
    PM[o] = m; PS[o] = s; PI[o] = (float)bi;
  }
}

// ---------------- k3b: merge g-chunk partials -> outputs -----------------
__device__ inline void lse_merge(float& m, float& s, int& i, float om, float os, int oi) {
  if (om == -INFINITY) return;
  if (m == -INFINITY) { m = om; s = os; i = oi; return; }
  if (om > m)       { s = s * __expf(m - om) + os; m = om; i = oi; }
  else if (om < m)  { s = s + os * __expf(om - m); }
  else              { s += os; i = (oi < i) ? oi : i; }
}

__global__ __launch_bounds__(256) void k3b(const int* __restrict__ verb_roles,
                                           const int* __restrict__ group_len,
                                           const float* __restrict__ PM,
                                           const float* __restrict__ PS,
                                           const float* __restrict__ PI,
                                           float* __restrict__ out) {
  const int idx = blockIdx.x * 256 + threadIdx.x;
  if (idx >= kV * kMR * kB) return;
  const int pr = idx >> 4;        // v*kMR + s
  const int b = idx & 15;
  const int v = pr / kMR, s = pr % kMR;
  const size_t o = ((size_t)b * kV + v) * kMR + s;
  const int r = verb_roles[pr];
  if (r < 0) {
    out[O_VRN + o] = 0.f; out[O_VRM + o] = 0.f; out[O_VRI + o] = 0.f;
    return;
  }
  const int glen = group_len[r];
  const int ngc = (glen + kGCH - 1) / kGCH;
  float M = -INFINITY, S = 0.f; int I = 0;
  for (int gc = 0; gc < ngc; gc++) {
    size_t po = ((size_t)pr * kB + b) * kGC + gc;
    lse_merge(M, S, I, PM[po], PS[po], (int)PI[po]);
  }
  out[O_VRN + o] = M + logf(S);
  out[O_VRM + o] = M;
  out[O_VRI + o] = (float)I;
}

// ---------------- k4: v_max, v_marginal LSE -> norm ----------------------
__global__ __launch_bounds__(256) void k4(float* __restrict__ out) {
  const int b = blockIdx.x;
  const int tid = threadIdx.x;
  float M = -INFINITY, S = 0.f;
  for (int v = tid; v < kV; v += 256) {
    float sm = 0.f, sx = 0.f;
#pragma unroll
    for (int s = 0; s < kMR; s++) {
      size_t o = ((size_t)b * kV + v) * kMR + s;
      sm += out[O_VRN + o];
      sx += out[O_VRM + o];
    }
    float vp = out[O_VPOT + (size_t)b * kV + v];
    float vm = sm + vp;
    out[O_VMAX + (size_t)b * kV + v] = sx + vp;
    float nm = fmaxf(M, vm);
    S = S * __expf(M - nm) + __expf(vm - nm);
    M = nm;
  }
#pragma unroll
  for (int off = 1; off < 64; off <<= 1) {
    float om = __shfl_xor(M, off);
    float os = __shfl_xor(S, off);
    if (om != -INFINITY) {
      if (M == -INFINITY) { M = om; S = os; }
      else if (om > M) { S = S * __expf(M - om) + os; M = om; }
      else { S += os * __expf(om - M); }
    }
  }
  __shared__ float rm2[4], rs2[4];
  const int wave = tid >> 6, lane = tid & 63;
  if (lane == 0) { rm2[wave] = M; rs2[wave] = S; }
  __syncthreads();
  if (tid == 0) {
    float Mm = rm2[0], Ss = rs2[0];
    for (int w = 1; w < 4; w++) {
      float om = rm2[w], os = rs2[w];
      if (om > Mm) { Ss = Ss * __expf(Mm - om) + os; Mm = om; }
      else { Ss += os * __expf(om - Mm); }
    }
    out[O_NORM + b] = Mm + logf(Ss);
  }
}

extern "C" void kernel_launch(void* const* d_in, const int* in_sizes, int n_in,
                              void* d_out, int out_size, void* d_ws, size_t ws_size,
                              hipStream_t stream) {
  const float* rep = (const float*)d_in[0];
  const float* Wv  = (const float*)d_in[1];
  const float* bv  = (const float*)d_in[2];
  const float* Wr  = (const float*)d_in[3];
  const float* br  = (const float*)d_in[4];
  const float* aiw = (const float*)d_in[5];
  const float* aib = (const float*)d_in[6];
  const float* aow = (const float*)d_in[7];
  const float* aob = (const float*)d_in[8];
  const float* Wn  = (const float*)d_in[9];
  const float* bnn = (const float*)d_in[10];
  const int* vrl   = (const int*)d_in[11];
  const int* gl    = (const int*)d_in[12];
  float* out = (float*)d_out;
  float* ws  = (float*)d_ws;
  int* icnt  = (int*)(ws + WS_CNT);
  int* ipair = (int*)(ws + WS_PAIR);

  k1a<<<dim3((kC1 + 255) / 256, kNDS), 256, 0, stream>>>(rep, Wv, Wr, ws + WS_PART);
  k1b<<<(kB * kC1 + 255) / 256, 256, 0, stream>>>(ws + WS_PART, bv, br, out, ws + WS_NODE);
  k0<<<1, 256, 0, stream>>>(vrl, icnt, ipair);
  k2<<<kV, 256, 0, stream>>>(ws + WS_NODE, vrl, aiw, aib, aow, aob, ws + WS_X);
  k3a<<<dim3(kR, kGC), 512, 0, stream>>>(ws + WS_X, icnt, ipair, gl, Wn, bnn,
                                         ws + WS_PM, ws + WS_PS, ws + WS_PI);
  k3b<<<(kV * kMR * kB + 255) / 256, 256, 0, stream>>>(vrl, gl, ws + WS_PM, ws + WS_PS,
                                                       ws + WS_PI, out);
  k4<<<kB, 256, 0, stream>>>(out);
}

// Round 4
// 316.466 us; speedup vs baseline: 4.7654x; 1.1168x over previous
//
#include <hip/hip_runtime.h>
#include <math.h>

// Problem constants (from setup_inputs)
constexpr int kB = 16;      // batch
constexpr int kD = 2048;    // rep dim
constexpr int kV = 504;     // verbs
constexpr int kR = 190;     // roles
constexpr int kH = 32;      // hidden
constexpr int kMR = 6;      // max roles/verb
constexpr int kG = 2000;    // group size
constexpr int kL = 3;       // attn layers
constexpr int kNH = 4;      // heads
constexpr int kHD = 8;      // head dim
constexpr int kC1 = kV + kR * kH;   // 6584 fused GEMM columns
constexpr int kNDS = 8;             // d-splits for k1a
constexpr int kDCH = kD / kNDS;     // 256

// k3 role-major params
constexpr int kMAXP = 64;   // max (v,s) pairs stored per role (mean 9.3)
constexpr int kGCH = 512;   // g-chunk length
constexpr int kGC = 4;      // number of g chunks (covers kG=2000)

// ws layout (float offsets).  REST is time-shared:
//   phase 1 (k1a/k1b): PART partials (kNDS*kB*kC1 = 842752 floats)
//   phase 2 (k0/k3a/k3b): PM/PS/PI partials + role lists (~593K floats)
constexpr size_t WS_NODE = 0;                           // kB*kR*kH      = 97280
constexpr size_t WS_X    = WS_NODE + (size_t)kB*kR*kH;  // kV*kMR*kB*kH  = 1548288
constexpr size_t WS_REST = WS_X + (size_t)kV*kMR*kB*kH;
constexpr size_t WS_PART = WS_REST;
constexpr size_t WS_PM   = WS_REST;                               // kV*kMR*kB*kGC
constexpr size_t WS_PS   = WS_PM + (size_t)kV*kMR*kB*kGC;
constexpr size_t WS_PI   = WS_PS + (size_t)kV*kMR*kB*kGC;
constexpr size_t WS_CNT  = WS_PI + (size_t)kV*kMR*kB*kGC;         // kR ints
constexpr size_t WS_PAIR = WS_CNT + kR;                           // kR*kMAXP ints

// out layout (float offsets), tuple concatenated flat
constexpr size_t O_VPOT = 0;                       // (B,V)
constexpr size_t O_NORM = O_VPOT + (size_t)kB*kV;  // (B,)
constexpr size_t O_VMAX = O_NORM + kB;             // (B,V)
constexpr size_t O_VRN  = O_VMAX + (size_t)kB*kV;  // (B,V,MR)
constexpr size_t O_VRM  = O_VRN + (size_t)kB*kV*kMR;
constexpr size_t O_VRI  = O_VRM + (size_t)kB*kV*kMR;

// ---------------- k1a: rep @ [W_v | W_r], d-split partials ----------------
__global__ __launch_bounds__(256) void k1a(const float* __restrict__ rep,
                                           const float* __restrict__ Wv,
                                           const float* __restrict__ Wr,
                                           float* __restrict__ part) {
  __shared__ float rl[kB][kDCH];
  const int tid = threadIdx.x;
  const int col = blockIdx.x * 256 + tid;
  const int d0 = blockIdx.y * kDCH;
  for (int i = tid; i < kB * kDCH; i += 256) {
    int b = i >> 8, dd = i & (kDCH - 1);
    rl[b][dd] = rep[b * kD + d0 + dd];
  }
  __syncthreads();
  if (col >= kC1) return;
  const float* Wp;
  int stride;
  if (col < kV) { Wp = Wv + (size_t)d0 * kV + col; stride = kV; }
  else          { Wp = Wr + (size_t)d0 * (kR*kH) + (col - kV); stride = kR*kH; }
  float acc[kB];
#pragma unroll
  for (int b = 0; b < kB; b++) acc[b] = 0.f;
  for (int dd = 0; dd < kDCH; dd++) {
    float w = Wp[(size_t)dd * stride];
#pragma unroll
    for (int b = 0; b < kB; b++) acc[b] += rl[b][dd] * w;
  }
  float* p = part + (size_t)(blockIdx.y * kB) * kC1 + col;
#pragma unroll
  for (int b = 0; b < kB; b++) p[(size_t)b * kC1] = acc[b];
}

// ---------------- k1b: reduce partials + bias, scatter to out/node -------
__global__ __launch_bounds__(256) void k1b(const float* __restrict__ part,
                                           const float* __restrict__ bv,
                                           const float* __restrict__ br,
                                           float* __restrict__ out,
                                           float* __restrict__ node) {
  int idx = blockIdx.x * 256 + threadIdx.x;
  if (idx >= kB * kC1) return;
  int b = idx / kC1, col = idx % kC1;
  float s = 0.f;
#pragma unroll
  for (int ds = 0; ds < kNDS; ds++) s += part[(size_t)(ds * kB + b) * kC1 + col];
  if (col < kV) out[O_VPOT + (size_t)b * kV + col] = s + bv[col];
  else          node[(size_t)b * (kR*kH) + (col - kV)] = s + br[col - kV];
}

// ---------------- k0: build role -> pair lists ---------------------------
__global__ __launch_bounds__(256) void k0(const int* __restrict__ verb_roles,
                                          int* __restrict__ cnt,
                                          int* __restrict__ pairs) {
  const int tid = threadIdx.x;
  for (int i = tid; i < kR; i += 256) cnt[i] = 0;
  __syncthreads();
  for (int i = tid; i < kV * kMR; i += 256) {
    int r = verb_roles[i];
    if (r >= 0) {
      int pos = atomicAdd(&cnt[r], 1);
      if (pos < kMAXP) pairs[r * kMAXP + pos] = i;   // i = v*kMR + s
    }
  }
}

// ---------------- k2: per-verb 3-layer MHA -------------------------------
__global__ __launch_bounds__(256) void k2(const float* __restrict__ node,
                                          const int* __restrict__ verb_roles,
                                          const float* __restrict__ in_w,
                                          const float* __restrict__ in_b,
                                          const float* __restrict__ out_w,
                                          const float* __restrict__ out_b,
                                          float* __restrict__ xout) {
  __shared__ float xs[kMR][kB][kH + 1];
  __shared__ float qkv[kMR][kB][3*kH + 1];
  __shared__ float ob[kMR][kB][kH + 1];
  __shared__ float wi[3*kH][kH + 1];
  __shared__ float bi[3*kH];
  __shared__ float wo[kH][kH + 1];
  __shared__ float bo[kH];
  __shared__ int roles[kMR];
  const int v = blockIdx.x;
  const int tid = threadIdx.x;
  if (tid < kMR) roles[tid] = verb_roles[v * kMR + tid];
  __syncthreads();
  for (int i = tid; i < kMR * kB * kH; i += 256) {
    int s = i / (kB * kH), rm = i % (kB * kH), b = rm / kH, h = rm % kH;
    int r = roles[s] < 0 ? 0 : roles[s];
    xs[s][b][h] = node[(size_t)b * (kR*kH) + r * kH + h];
  }
  for (int l = 0; l < kL; l++) {
    for (int i = tid; i < 3*kH*kH; i += 256) wi[i / kH][i % kH] = in_w[(size_t)l*3*kH*kH + i];
    for (int i = tid; i < kH*kH; i += 256)   wo[i / kH][i % kH] = out_w[(size_t)l*kH*kH + i];
    if (tid < 3*kH) bi[tid] = in_b[l*3*kH + tid];
    if (tid < kH)   bo[tid] = out_b[l*kH + tid];
    __syncthreads();
    for (int i = tid; i < kMR*kB*3*kH; i += 256) {
      int s = i / (kB*3*kH), rm = i % (kB*3*kH), b = rm / (3*kH), f = rm % (3*kH);
      float a = bi[f];
#pragma unroll
      for (int h = 0; h < kH; h++) a += xs[s][b][h] * wi[f][h];
      qkv[s][b][f] = a;
    }
    __syncthreads();
    if (tid < kB * kNH) {
      const int b = tid & (kB - 1);
      const int hh = tid >> 4;
      const float scale = 0.35355339059327373f; // 1/sqrt(8)
      float sc[kMR][kMR];
      for (int s = 0; s < kMR; s++) {
        float q[kHD];
#pragma unroll
        for (int d = 0; d < kHD; d++) q[d] = qkv[s][b][hh*kHD + d] * scale;
        for (int t = 0; t < kMR; t++) {
          float a = 0.f;
#pragma unroll
          for (int d = 0; d < kHD; d++) a += q[d] * qkv[t][b][kH + hh*kHD + d];
          sc[s][t] = a;
        }
      }
      for (int s = 0; s < kMR; s++) {
        float m = -INFINITY;
        for (int t = 0; t < kMR; t++) if (roles[t] >= 0 && sc[s][t] > m) m = sc[s][t];
        float sum = 0.f;
        for (int t = 0; t < kMR; t++) {
          float e = (roles[t] >= 0) ? __expf(sc[s][t] - m) : 0.f;
          sc[s][t] = e; sum += e;
        }
        float inv = 1.f / sum;
        for (int t = 0; t < kMR; t++) sc[s][t] *= inv;
      }
      float o[kMR][kHD];
      for (int s = 0; s < kMR; s++)
#pragma unroll
        for (int d = 0; d < kHD; d++) o[s][d] = 0.f;
      for (int t = 0; t < kMR; t++) {
#pragma unroll
        for (int d = 0; d < kHD; d++) {
          float vv = qkv[t][b][2*kH + hh*kHD + d];
          for (int s = 0; s < kMR; s++) o[s][d] += sc[s][t] * vv;
        }
      }
      for (int s = 0; s < kMR; s++)
#pragma unroll
        for (int d = 0; d < kHD; d++) ob[s][b][hh*kHD + d] = o[s][d];
    }
    __syncthreads();
    for (int i = tid; i < kMR*kB*kH; i += 256) {
      int s = i / (kB*kH), rm = i % (kB*kH), b = rm / kH, f = rm % kH;
      float a = bo[f];
#pragma unroll
      for (int h = 0; h < kH; h++) a += ob[s][b][h] * wo[f][h];
      xs[s][b][f] = a;
    }
    __syncthreads();
  }
  for (int i = tid; i < kMR*kB*kH; i += 256) {
    int s = i / (kB*kH), rm = i % (kB*kH), b = rm / kH, h = rm % kH;
    xout[(((size_t)v*kMR + s)*kB + b)*kH + h] = xs[s][b][h];
  }
}

// ---------------- k3a: role-major logits, g-split across waves -----------
// block = (role r, g-chunk gc); 512 threads = 8 waves.
// Wave w owns g-slice [64w, 64w+64) of the staged 512-chunk; within a wave,
// lane = (b, pair-slot[0..4)). Pairs loop by quads; after each quad a 6KB
// LDS buffer merges the 8 wave-slices (ascending g => first-occurrence
// argmax preserved) and writes the same per-gc partials as before.
__global__ __launch_bounds__(512) void k3a(const float* __restrict__ xw,
                                           const int* __restrict__ cnt,
                                           const int* __restrict__ pairs,
                                           const int* __restrict__ group_len,
                                           const float* __restrict__ Wn,
                                           const float* __restrict__ bn,
                                           float* __restrict__ PM,
                                           float* __restrict__ PS,
                                           float* __restrict__ PI) {
  __shared__ float4 Wl[kGCH][9];   // [g][0..7]=W row, [8].x=bias
  __shared__ float mbM[8][4][kB], mbS[8][4][kB], mbI[8][4][kB];
  const int r = blockIdx.x;
  const int gc = blockIdx.y;
  const int glen = group_len[r];
  const int g0 = gc * kGCH;
  if (g0 >= glen) return;
  int c = cnt[r]; if (c > kMAXP) c = kMAXP;
  if (c == 0) return;
  const int gn = (g0 + kGCH < glen) ? kGCH : (glen - g0);
  const int tid = threadIdx.x;
  const float* W = Wn + (size_t)r * kH * kG + g0;
  const float* bias = bn + (size_t)r * kG + g0;
  // stage: coalesced global reads (consecutive g per lane)
  for (int g = tid; g < gn; g += 512) {
    float* row = (float*)&Wl[g][0];
#pragma unroll
    for (int h = 0; h < kH; h++) row[h] = W[(size_t)h * kG + g];
    row[kH] = bias[g];
  }
  __syncthreads();
  const int wave = tid >> 6, lane = tid & 63;
  const int b = lane & 15, slot = lane >> 4;
  const int gw0 = (wave * 64 < gn) ? wave * 64 : gn;
  const int gw1 = (wave * 64 + 64 < gn) ? wave * 64 + 64 : gn;
  const int nq = (c + 3) >> 2;
  for (int q = 0; q < nq; q++) {
    const int p = 4 * q + slot;
    const bool valid = p < c;
    const int pr = pairs[r * kMAXP + (valid ? p : c - 1)];
    float4 x[8];
    const float4* xp = (const float4*)(xw + ((size_t)pr * kB + b) * kH);
#pragma unroll
    for (int j = 0; j < 8; j++) x[j] = xp[j];
    float m = -INFINITY, s = 0.f; int bi = 0;
    for (int g = gw0; g < gw1; g++) {
      const float4* w = &Wl[g][0];
      float a0 = 0.f, a1 = 0.f, a2 = 0.f, a3 = 0.f;
#pragma unroll
      for (int j = 0; j < 8; j += 4) {
        float4 w0 = w[j], w1 = w[j+1], w2 = w[j+2], w3 = w[j+3];
        a0 = fmaf(x[j].x, w0.x, fmaf(x[j].y, w0.y, fmaf(x[j].z, w0.z, fmaf(x[j].w, w0.w, a0))));
        a1 = fmaf(x[j+1].x, w1.x, fmaf(x[j+1].y, w1.y, fmaf(x[j+1].z, w1.z, fmaf(x[j+1].w, w1.w, a1))));
        a2 = fmaf(x[j+2].x, w2.x, fmaf(x[j+2].y, w2.y, fmaf(x[j+2].z, w2.z, fmaf(x[j+2].w, w2.w, a2))));
        a3 = fmaf(x[j+3].x, w3.x, fmaf(x[j+3].y, w3.y, fmaf(x[j+3].z, w3.z, fmaf(x[j+3].w, w3.w, a3))));
      }
      float acc = ((a0 + a1) + (a2 + a3)) + w[8].x;
      float d = acc - m;
      bool gt = d > 0.f;
      float e = __expf(gt ? -d : d);   // first iter: exp(-inf) = 0
      s = gt ? fmaf(s, e, 1.f) : s + e;
      bi = gt ? g0 + g : bi;
      m = gt ? acc : m;
    }
    mbM[wave][slot][b] = valid ? m : -INFINITY;
    mbS[wave][slot][b] = s;
    mbI[wave][slot][b] = (float)bi;
    __syncthreads();
    if (tid < 64) {
      const int pl = tid >> 4, bb = tid & 15;
      const int pg = 4 * q + pl;
      if (pg < c) {
        float M = -INFINITY, S = 0.f; int I = 0;
#pragma unroll
        for (int w8 = 0; w8 < 8; w8++) {
          float om = mbM[w8][pl][bb];
          float os = mbS[w8][pl][bb];
          int oi = (int)mbI[w8][pl][bb];
          if (om != -INFINITY) {
            if (M == -INFINITY)      { M = om; S = os; I = oi; }
            else if (om > M)         { S = S * __expf(M - om) + os; M = om; I = oi; }
            else if (om < M)         { S = S + os * __expf(om - M); }
            else                     { S += os; I = (oi < I) ? oi : I; }
          }
        }
        const int pr2 = pairs[r * kMAXP + pg];
        size_t o = ((size_t)pr2 * kB + bb) * kGC + gc;
        PM[o] = M; PS[o] = S; PI[o] = (float)I;
      }
    }
    __syncthreads();
  }
}

// ---------------- k3b: merge g-chunk partials -> outputs -----------------
__device__ inline void lse_merge(float& m, float& s, int& i, float om, float os, int oi) {
  if (om == -INFINITY) return;
  if (m == -INFINITY) { m = om; s = os; i = oi; return; }
  if (om > m)       { s = s * __expf(m - om) + os; m = om; i = oi; }
  else if (om < m)  { s = s + os * __expf(om - m); }
  else              { s += os; i = (oi < i) ? oi : i; }
}

__global__ __launch_bounds__(256) void k3b(const int* __restrict__ verb_roles,
                                           const int* __restrict__ group_len,
                                           const float* __restrict__ PM,
                                           const float* __restrict__ PS,
                                           const float* __restrict__ PI,
                                           float* __restrict__ out) {
  const int idx = blockIdx.x * 256 + threadIdx.x;
  if (idx >= kV * kMR * kB) return;
  const int pr = idx >> 4;        // v*kMR + s
  const int b = idx & 15;
  const int v = pr / kMR, s = pr % kMR;
  const size_t o = ((size_t)b * kV + v) * kMR + s;
  const int r = verb_roles[pr];
  if (r < 0) {
    out[O_VRN + o] = 0.f; out[O_VRM + o] = 0.f; out[O_VRI + o] = 0.f;
    return;
  }
  const int glen = group_len[r];
  const int ngc = (glen + kGCH - 1) / kGCH;
  float M = -INFINITY, S = 0.f; int I = 0;
  for (int gc = 0; gc < ngc; gc++) {
    size_t po = ((size_t)pr * kB + b) * kGC + gc;
    lse_merge(M, S, I, PM[po], PS[po], (int)PI[po]);
  }
  out[O_VRN + o] = M + logf(S);
  out[O_VRM + o] = M;
  out[O_VRI + o] = (float)I;
}

// ---------------- k4: v_max, v_marginal LSE -> norm ----------------------
__global__ __launch_bounds__(256) void k4(float* __restrict__ out) {
  const int b = blockIdx.x;
  const int tid = threadIdx.x;
  float M = -INFINITY, S = 0.f;
  for (int v = tid; v < kV; v += 256) {
    float sm = 0.f, sx = 0.f;
#pragma unroll
    for (int s = 0; s < kMR; s++) {
      size_t o = ((size_t)b * kV + v) * kMR + s;
      sm += out[O_VRN + o];
      sx += out[O_VRM + o];
    }
    float vp = out[O_VPOT + (size_t)b * kV + v];
    float vm = sm + vp;
    out[O_VMAX + (size_t)b * kV + v] = sx + vp;
    float nm = fmaxf(M, vm);
    S = S * __expf(M - nm) + __expf(vm - nm);
    M = nm;
  }
#pragma unroll
  for (int off = 1; off < 64; off <<= 1) {
    float om = __shfl_xor(M, off);
    float os = __shfl_xor(S, off);
    if (om != -INFINITY) {
      if (M == -INFINITY) { M = om; S = os; }
      else if (om > M) { S = S * __expf(M - om) + os; M = om; }
      else { S += os * __expf(om - M); }
    }
  }
  __shared__ float rm2[4], rs2[4];
  const int wave = tid >> 6, lane = tid & 63;
  if (lane == 0) { rm2[wave] = M; rs2[wave] = S; }
  __syncthreads();
  if (tid == 0) {
    float Mm = rm2[0], Ss = rs2[0];
    for (int w = 1; w < 4; w++) {
      float om = rm2[w], os = rs2[w];
      if (om > Mm) { Ss = Ss * __expf(Mm - om) + os; Mm = om; }
      else { Ss += os * __expf(om - Mm); }
    }
    out[O_NORM + b] = Mm + logf(Ss);
  }
}

extern "C" void kernel_launch(void* const* d_in, const int* in_sizes, int n_in,
                              void* d_out, int out_size, void* d_ws, size_t ws_size,
                              hipStream_t stream) {
  const float* rep = (const float*)d_in[0];
  const float* Wv  = (const float*)d_in[1];
  const float* bv  = (const float*)d_in[2];
  const float* Wr  = (const float*)d_in[3];
  const float* br  = (const float*)d_in[4];
  const float* aiw = (const float*)d_in[5];
  const float* aib = (const float*)d_in[6];
  const float* aow = (const float*)d_in[7];
  const float* aob = (const float*)d_in[8];
  const float* Wn  = (const float*)d_in[9];
  const float* bnn = (const float*)d_in[10];
  const int* vrl   = (const int*)d_in[11];
  const int* gl    = (const int*)d_in[12];
  float* out = (float*)d_out;
  float* ws  = (float*)d_ws;
  int* icnt  = (int*)(ws + WS_CNT);
  int* ipair = (int*)(ws + WS_PAIR);

  k1a<<<dim3((kC1 + 255) / 256, kNDS), 256, 0, stream>>>(rep, Wv, Wr, ws + WS_PART);
  k1b<<<(kB * kC1 + 255) / 256, 256, 0, stream>>>(ws + WS_PART, bv, br, out, ws + WS_NODE);
  k0<<<1, 256, 0, stream>>>(vrl, icnt, ipair);
  k2<<<kV, 256, 0, stream>>>(ws + WS_NODE, vrl, aiw, aib, aow, aob, ws + WS_X);
  k3a<<<dim3(kR, kGC), 512, 0, stream>>>(ws + WS_X, icnt, ipair, gl, Wn, bnn,
                                         ws + WS_PM, ws + WS_PS, ws + WS_PI);
  k3b<<<(kV * kMR * kB + 255) / 256, 256, 0, stream>>>(vrl, gl, ws + WS_PM, ws + WS_PS,
                                                       ws + WS_PI, out);
  k4<<<kB, 256, 0, stream>>>(out);
}

// Round 5
// 301.596 us; speedup vs baseline: 5.0003x; 1.0493x over previous
//
#include <hip/hip_runtime.h>
#include <math.h>

// Problem constants (from setup_inputs)
constexpr int kB = 16;      // batch
constexpr int kD = 2048;    // rep dim
constexpr int kV = 504;     // verbs
constexpr int kR = 190;     // roles
constexpr int kH = 32;      // hidden
constexpr int kMR = 6;      // max roles/verb
constexpr int kG = 2000;    // group size
constexpr int kL = 3;       // attn layers
constexpr int kNH = 4;      // heads
constexpr int kHD = 8;      // head dim
constexpr int kC1 = kV + kR * kH;   // 6584 fused GEMM columns
constexpr int kNDS = 8;             // d-splits for k1a
constexpr int kDCH = kD / kNDS;     // 256

// k3 role-major params
constexpr int kMAXP = 64;   // max (v,s) pairs stored per role (mean 9.3)
constexpr int kGCH = 500;   // g-chunk length (4 x 500 = 2000 = kG)
constexpr int kGC = 4;      // number of g chunks

// ws layout (float offsets).  REST is time-shared:
//   phase 1 (k1a/k1b): PART partials (kNDS*kB*kC1 = 842752 floats)
//   phase 2 (k0/k3a/k3b): PM/PS/PI partials + role lists (~593K floats)
constexpr size_t WS_NODE = 0;                           // kB*kR*kH      = 97280
constexpr size_t WS_X    = WS_NODE + (size_t)kB*kR*kH;  // kV*kMR*kB*kH  = 1548288
constexpr size_t WS_REST = WS_X + (size_t)kV*kMR*kB*kH;
constexpr size_t WS_PART = WS_REST;
constexpr size_t WS_PM   = WS_REST;                               // kV*kMR*kB*kGC
constexpr size_t WS_PS   = WS_PM + (size_t)kV*kMR*kB*kGC;
constexpr size_t WS_PI   = WS_PS + (size_t)kV*kMR*kB*kGC;
constexpr size_t WS_CNT  = WS_PI + (size_t)kV*kMR*kB*kGC;         // kR ints
constexpr size_t WS_PAIR = WS_CNT + kR;                           // kR*kMAXP ints

// out layout (float offsets), tuple concatenated flat
constexpr size_t O_VPOT = 0;                       // (B,V)
constexpr size_t O_NORM = O_VPOT + (size_t)kB*kV;  // (B,)
constexpr size_t O_VMAX = O_NORM + kB;             // (B,V)
constexpr size_t O_VRN  = O_VMAX + (size_t)kB*kV;  // (B,V,MR)
constexpr size_t O_VRM  = O_VRN + (size_t)kB*kV*kMR;
constexpr size_t O_VRI  = O_VRM + (size_t)kB*kV*kMR;

__device__ inline float dot4(float4 a, float4 w, float acc) {
  return fmaf(a.x, w.x, fmaf(a.y, w.y, fmaf(a.z, w.z, fmaf(a.w, w.w, acc))));
}
__device__ inline float dot4s(const float* a, float4 w, float acc) {
  return fmaf(a[0], w.x, fmaf(a[1], w.y, fmaf(a[2], w.z, fmaf(a[3], w.w, acc))));
}

// ---------------- k1a: rep @ [W_v | W_r], d-split partials ----------------
__global__ __launch_bounds__(256) void k1a(const float* __restrict__ rep,
                                           const float* __restrict__ Wv,
                                           const float* __restrict__ Wr,
                                           float* __restrict__ part) {
  __shared__ float rl[kB][kDCH];
  const int tid = threadIdx.x;
  const int col = blockIdx.x * 256 + tid;
  const int d0 = blockIdx.y * kDCH;
  for (int i = tid; i < kB * kDCH; i += 256) {
    int b = i >> 8, dd = i & (kDCH - 1);
    rl[b][dd] = rep[b * kD + d0 + dd];
  }
  __syncthreads();
  if (col >= kC1) return;
  const float* Wp;
  int stride;
  if (col < kV) { Wp = Wv + (size_t)d0 * kV + col; stride = kV; }
  else          { Wp = Wr + (size_t)d0 * (kR*kH) + (col - kV); stride = kR*kH; }
  float acc[kB];
#pragma unroll
  for (int b = 0; b < kB; b++) acc[b] = 0.f;
  for (int dd = 0; dd < kDCH; dd++) {
    float w = Wp[(size_t)dd * stride];
#pragma unroll
    for (int b = 0; b < kB; b++) acc[b] += rl[b][dd] * w;
  }
  float* p = part + (size_t)(blockIdx.y * kB) * kC1 + col;
#pragma unroll
  for (int b = 0; b < kB; b++) p[(size_t)b * kC1] = acc[b];
}

// ---------------- k1b: reduce partials + bias, scatter to out/node -------
__global__ __launch_bounds__(256) void k1b(const float* __restrict__ part,
                                           const float* __restrict__ bv,
                                           const float* __restrict__ br,
                                           float* __restrict__ out,
                                           float* __restrict__ node) {
  int idx = blockIdx.x * 256 + threadIdx.x;
  if (idx >= kB * kC1) return;
  int b = idx / kC1, col = idx % kC1;
  float s = 0.f;
#pragma unroll
  for (int ds = 0; ds < kNDS; ds++) s += part[(size_t)(ds * kB + b) * kC1 + col];
  if (col < kV) out[O_VPOT + (size_t)b * kV + col] = s + bv[col];
  else          node[(size_t)b * (kR*kH) + (col - kV)] = s + br[col - kV];
}

// ---------------- k0: build role -> pair lists ---------------------------
__global__ __launch_bounds__(256) void k0(const int* __restrict__ verb_roles,
                                          int* __restrict__ cnt,
                                          int* __restrict__ pairs) {
  const int tid = threadIdx.x;
  for (int i = tid; i < kR; i += 256) cnt[i] = 0;
  __syncthreads();
  for (int i = tid; i < kV * kMR; i += 256) {
    int r = verb_roles[i];
    if (r >= 0) {
      int pos = atomicAdd(&cnt[r], 1);
      if (pos < kMAXP) pairs[r * kMAXP + pos] = i;   // i = v*kMR + s
    }
  }
}

// ---------------- k2: per-verb 3-layer MHA, x in registers ---------------
// block = 192 threads (3 waves) per verb. Thread t: row = t>>1 = s*16+b,
// half = t&1. x row lives in 8 float4 regs for the whole kernel. Weights
// in LDS at stride 36 (16B-aligned float4 rows, <=2-way banks). qkv buffer
// stride 97 (scalar ops, conflict-free). Attention: 384 (s,b,hh) units on
// 192 threads x2; o written into qkv's dead q-slice.
__global__ __launch_bounds__(192) void k2(const float* __restrict__ node,
                                          const int* __restrict__ verb_roles,
                                          const float* __restrict__ in_w,
                                          const float* __restrict__ in_b,
                                          const float* __restrict__ out_w,
                                          const float* __restrict__ out_b,
                                          float* __restrict__ xout) {
  __shared__ float wi[96][36];
  __shared__ float wo[32][36];
  __shared__ float bi[96];
  __shared__ float bo[32];
  __shared__ float qkv[kMR][kB][97];
  __shared__ int roles[kMR];
  const int v = blockIdx.x;
  const int tid = threadIdx.x;
  if (tid < kMR) roles[tid] = verb_roles[v * kMR + tid];
  __syncthreads();
  const int row = tid >> 1, half = tid & 1;
  const int s = row >> 4, b = row & 15;
  float4 x4[8];
  {
    int r = roles[s] < 0 ? 0 : roles[s];
    const float4* xp = (const float4*)(node + (size_t)b * (kR*kH) + r * kH);
#pragma unroll
    for (int j = 0; j < 8; j++) x4[j] = xp[j];
  }
  for (int l = 0; l < kL; l++) {
    for (int i = tid; i < 96*32; i += 192) wi[i >> 5][i & 31] = in_w[(size_t)l*96*32 + i];
    for (int i = tid; i < 32*32; i += 192) wo[i >> 5][i & 31] = out_w[(size_t)l*32*32 + i];
    if (tid < 96) bi[tid] = in_b[l*96 + tid];
    else if (tid < 128) bo[tid - 96] = out_b[l*32 + (tid - 96)];
    __syncthreads();
    // QKV: 48 cols per thread, x in regs, wi rows via float4
    for (int fi = 0; fi < 48; fi++) {
      const int f = 48 * half + fi;
      const float4* wr = (const float4*)&wi[f][0];
      float a0 = 0.f, a1 = 0.f, a2 = 0.f, a3 = 0.f;
#pragma unroll
      for (int j = 0; j < 8; j += 4) {
        a0 = dot4(x4[j],   wr[j],   a0);
        a1 = dot4(x4[j+1], wr[j+1], a1);
        a2 = dot4(x4[j+2], wr[j+2], a2);
        a3 = dot4(x4[j+3], wr[j+3], a3);
      }
      qkv[s][b][f] = ((a0 + a1) + (a2 + a3)) + bi[f];
    }
    __syncthreads();
    // attention: units (s,b,hh), 2 per thread
#pragma unroll
    for (int ui = 0; ui < 2; ui++) {
      const int u = tid + 192 * ui;
      const int us = u >> 6, uh = (u >> 4) & 3, ub = u & 15;
      float q[8];
#pragma unroll
      for (int d = 0; d < 8; d++) q[d] = qkv[us][ub][uh*8 + d] * 0.35355339059327373f;
      float sc[kMR];
      float mx = -INFINITY;
#pragma unroll
      for (int t = 0; t < kMR; t++) {
        float a = 0.f;
#pragma unroll
        for (int d = 0; d < 8; d++) a = fmaf(q[d], qkv[t][ub][32 + uh*8 + d], a);
        sc[t] = a;
        if (roles[t] >= 0 && a > mx) mx = a;
      }
      float sum = 0.f;
#pragma unroll
      for (int t = 0; t < kMR; t++) {
        float e = (roles[t] >= 0) ? __expf(sc[t] - mx) : 0.f;
        sc[t] = e; sum += e;
      }
      const float inv = 1.f / sum;
      float o[8];
#pragma unroll
      for (int d = 0; d < 8; d++) o[d] = 0.f;
#pragma unroll
      for (int t = 0; t < kMR; t++) {
        const float w = sc[t] * inv;
#pragma unroll
        for (int d = 0; d < 8; d++) o[d] = fmaf(w, qkv[t][ub][64 + uh*8 + d], o[d]);
      }
#pragma unroll
      for (int d = 0; d < 8; d++) qkv[us][ub][uh*8 + d] = o[d];  // own q-slot
    }
    __syncthreads();
    // out-proj: full 32 cols per thread (dup across halves), o row from LDS
    float orow[32];
#pragma unroll
    for (int h = 0; h < 32; h++) orow[h] = qkv[s][b][h];
    float xn[32];
    for (int c2 = 0; c2 < 32; c2++) {
      const float4* wr = (const float4*)&wo[c2][0];
      float a0 = 0.f, a1 = 0.f, a2 = 0.f, a3 = 0.f;
#pragma unroll
      for (int j = 0; j < 8; j += 4) {
        a0 = dot4s(&orow[4*j],      wr[j],   a0);
        a1 = dot4s(&orow[4*(j+1)],  wr[j+1], a1);
        a2 = dot4s(&orow[4*(j+2)],  wr[j+2], a2);
        a3 = dot4s(&orow[4*(j+3)],  wr[j+3], a3);
      }
      xn[c2] = ((a0 + a1) + (a2 + a3)) + bo[c2];
    }
#pragma unroll
    for (int j = 0; j < 8; j++) x4[j] = make_float4(xn[4*j], xn[4*j+1], xn[4*j+2], xn[4*j+3]);
    __syncthreads();
  }
  float4* xo4 = (float4*)(xout + (((size_t)v*kMR + s)*kB + b)*kH + half*16);
  if (half == 0) {
#pragma unroll
    for (int j = 0; j < 4; j++) xo4[j] = x4[j];
  } else {
#pragma unroll
    for (int j = 0; j < 4; j++) xo4[j] = x4[4 + j];
  }
}

// ---------------- k3a: role-major logits, 2 pairs/thread -----------------
// block = (role r, g-chunk gc); 256 threads = 4 waves x (16 b x 4 slots).
// Wave w owns g-slice [125w,125w+125); thread handles 2 pairs so each
// 8x-float4 W-row read feeds 64 FMA. W rows stride-36 in LDS (16B aligned).
__global__ __launch_bounds__(256) void k3a(const float* __restrict__ xw,
                                           const int* __restrict__ cnt,
                                           const int* __restrict__ pairs,
                                           const int* __restrict__ group_len,
                                           const float* __restrict__ Wn,
                                           const float* __restrict__ bn,
                                           float* __restrict__ PM,
                                           float* __restrict__ PS,
                                           float* __restrict__ PI) {
  __shared__ float Wl[kGCH * 36];
  __shared__ float Bl[kGCH];
  __shared__ float mbM[4][8][kB], mbS[4][8][kB], mbI[4][8][kB];
  const int r = blockIdx.x, gc = blockIdx.y;
  const int glen = group_len[r];
  const int g0 = gc * kGCH;
  if (g0 >= glen) return;
  int c = cnt[r]; if (c > kMAXP) c = kMAXP;
  if (c == 0) return;
  const int gn = (kGCH < glen - g0) ? kGCH : (glen - g0);
  const int tid = threadIdx.x;
  const float* W = Wn + (size_t)r * kH * kG + g0;
  const float* bias = bn + (size_t)r * kG + g0;
  for (int g = tid; g < gn; g += 256) {
#pragma unroll
    for (int h = 0; h < kH; h++) Wl[g * 36 + h] = W[(size_t)h * kG + g];
    Bl[g] = bias[g];
  }
  __syncthreads();
  const int wave = tid >> 6, lane = tid & 63;
  const int b = lane & 15, slot = lane >> 4;
  int gw0 = wave * 125, gw1 = gw0 + 125;
  gw0 = (gw0 < gn) ? gw0 : gn;
  gw1 = (gw1 < gn) ? gw1 : gn;
  const int nq = (c + 7) >> 3;
  for (int q = 0; q < nq; q++) {
    const int p0 = 8 * q + 2 * slot, p1 = p0 + 1;
    const bool v0 = p0 < c, v1 = p1 < c;
    const int pr0 = pairs[r * kMAXP + (v0 ? p0 : 0)];
    const int pr1 = pairs[r * kMAXP + (v1 ? p1 : 0)];
    float4 x0[8], x1[8];
    {
      const float4* xp0 = (const float4*)(xw + ((size_t)pr0 * kB + b) * kH);
      const float4* xp1 = (const float4*)(xw + ((size_t)pr1 * kB + b) * kH);
#pragma unroll
      for (int j = 0; j < 8; j++) { x0[j] = xp0[j]; x1[j] = xp1[j]; }
    }
    float m0 = -INFINITY, s0 = 0.f, m1 = -INFINITY, s1 = 0.f;
    int i0 = 0, i1 = 0;
    for (int g = gw0; g < gw1; g++) {
      const float4* wr = (const float4*)&Wl[g * 36];
      const float bg = Bl[g];
      float a0 = 0.f, a1 = 0.f, a2 = 0.f, a3 = 0.f;
      float c0 = 0.f, c1 = 0.f, c2 = 0.f, c3 = 0.f;
#pragma unroll
      for (int j = 0; j < 8; j += 4) {
        float4 w0 = wr[j], w1 = wr[j+1], w2 = wr[j+2], w3 = wr[j+3];
        a0 = dot4(x0[j],   w0, a0);  c0 = dot4(x1[j],   w0, c0);
        a1 = dot4(x0[j+1], w1, a1);  c1 = dot4(x1[j+1], w1, c1);
        a2 = dot4(x0[j+2], w2, a2);  c2 = dot4(x1[j+2], w2, c2);
        a3 = dot4(x0[j+3], w3, a3);  c3 = dot4(x1[j+3], w3, c3);
      }
      const float acc0 = ((a0 + a1) + (a2 + a3)) + bg;
      const float acc1 = ((c0 + c1) + (c2 + c3)) + bg;
      {
        float d = acc0 - m0; bool gt = d > 0.f;
        float e = __expf(gt ? -d : d);
        s0 = gt ? fmaf(s0, e, 1.f) : s0 + e;
        i0 = gt ? g0 + g : i0;  m0 = gt ? acc0 : m0;
      }
      {
        float d = acc1 - m1; bool gt = d > 0.f;
        float e = __expf(gt ? -d : d);
        s1 = gt ? fmaf(s1, e, 1.f) : s1 + e;
        i1 = gt ? g0 + g : i1;  m1 = gt ? acc1 : m1;
      }
    }
    mbM[wave][2*slot][b]   = v0 ? m0 : -INFINITY;
    mbS[wave][2*slot][b]   = s0;
    mbI[wave][2*slot][b]   = (float)i0;
    mbM[wave][2*slot+1][b] = v1 ? m1 : -INFINITY;
    mbS[wave][2*slot+1][b] = s1;
    mbI[wave][2*slot+1][b] = (float)i1;
    __syncthreads();
    if (tid < 128) {
      const int pl = tid >> 4, bb = tid & 15;
      const int pg = 8 * q + pl;
      if (pg < c) {
        float M = -INFINITY, S = 0.f; int I = 0;
#pragma unroll
      for (int w = 0; w < 4; w++) {
          float om = mbM[w][pl][bb];
          float os = mbS[w][pl][bb];
          int oi = (int)mbI[w][pl][bb];
          if (om != -INFINITY) {
            if (M == -INFINITY)      { M = om; S = os; I = oi; }
            else if (om > M)         { S = S * __expf(M - om) + os; M = om; I = oi; }
            else if (om < M)         { S = S + os * __expf(om - M); }
            else                     { S += os; I = (oi < I) ? oi : I; }
          }
        }
        const int pr2 = pairs[r * kMAXP + pg];
        size_t o = ((size_t)pr2 * kB + bb) * kGC + gc;
        PM[o] = M; PS[o] = S; PI[o] = (float)I;
      }
    }
    __syncthreads();
  }
}

// ---------------- k3b: merge g-chunk partials -> outputs -----------------
__device__ inline void lse_merge(float& m, float& s, int& i, float om, float os, int oi) {
  if (om == -INFINITY) return;
  if (m == -INFINITY) { m = om; s = os; i = oi; return; }
  if (om > m)       { s = s * __expf(m - om) + os; m = om; i = oi; }
  else if (om < m)  { s = s + os * __expf(om - m); }
  else              { s += os; i = (oi < i) ? oi : i; }
}

__global__ __launch_bounds__(256) void k3b(const int* __restrict__ verb_roles,
                                           const int* __restrict__ group_len,
                                           const float* __restrict__ PM,
                                           const float* __restrict__ PS,
                                           const float* __restrict__ PI,
                                           float* __restrict__ out) {
  const int idx = blockIdx.x * 256 + threadIdx.x;
  if (idx >= kV * kMR * kB) return;
  const int pr = idx >> 4;        // v*kMR + s
  const int b = idx & 15;
  const int v = pr / kMR, s = pr % kMR;
  const size_t o = ((size_t)b * kV + v) * kMR + s;
  const int r = verb_roles[pr];
  if (r < 0) {
    out[O_VRN + o] = 0.f; out[O_VRM + o] = 0.f; out[O_VRI + o] = 0.f;
    return;
  }
  const int glen = group_len[r];
  const int ngc = (glen + kGCH - 1) / kGCH;
  float M = -INFINITY, S = 0.f; int I = 0;
  for (int gc = 0; gc < ngc; gc++) {
    size_t po = ((size_t)pr * kB + b) * kGC + gc;
    lse_merge(M, S, I, PM[po], PS[po], (int)PI[po]);
  }
  out[O_VRN + o] = M + logf(S);
  out[O_VRM + o] = M;
  out[O_VRI + o] = (float)I;
}

// ---------------- k4: v_max, v_marginal LSE -> norm ----------------------
__global__ __launch_bounds__(256) void k4(float* __restrict__ out) {
  const int b = blockIdx.x;
  const int tid = threadIdx.x;
  float M = -INFINITY, S = 0.f;
  for (int v = tid; v < kV; v += 256) {
    float sm = 0.f, sx = 0.f;
#pragma unroll
    for (int s = 0; s < kMR; s++) {
      size_t o = ((size_t)b * kV + v) * kMR + s;
      sm += out[O_VRN + o];
      sx += out[O_VRM + o];
    }
    float vp = out[O_VPOT + (size_t)b * kV + v];
    float vm = sm + vp;
    out[O_VMAX + (size_t)b * kV + v] = sx + vp;
    float nm = fmaxf(M, vm);
    S = S * __expf(M - nm) + __expf(vm - nm);
    M = nm;
  }
#pragma unroll
  for (int off = 1; off < 64; off <<= 1) {
    float om = __shfl_xor(M, off);
    float os = __shfl_xor(S, off);
    if (om != -INFINITY) {
      if (M == -INFINITY) { M = om; S = os; }
      else if (om > M) { S = S * __expf(M - om) + os; M = om; }
      else { S += os * __expf(om - M); }
    }
  }
  __shared__ float rm2[4], rs2[4];
  const int wave = tid >> 6, lane = tid & 63;
  if (lane == 0) { rm2[wave] = M; rs2[wave] = S; }
  __syncthreads();
  if (tid == 0) {
    float Mm = rm2[0], Ss = rs2[0];
    for (int w = 1; w < 4; w++) {
      float om = rm2[w], os = rs2[w];
      if (om > Mm) { Ss = Ss * __expf(Mm - om) + os; Mm = om; }
      else { Ss += os * __expf(om - Mm); }
    }
    out[O_NORM + b] = Mm + logf(Ss);
  }
}

extern "C" void kernel_launch(void* const* d_in, const int* in_sizes, int n_in,
                              void* d_out, int out_size, void* d_ws, size_t ws_size,
                              hipStream_t stream) {
  const float* rep = (const float*)d_in[0];
  const float* Wv  = (const float*)d_in[1];
  const float* bv  = (const float*)d_in[2];
  const float* Wr  = (const float*)d_in[3];
  const float* br  = (const float*)d_in[4];
  const float* aiw = (const float*)d_in[5];
  const float* aib = (const float*)d_in[6];
  const float* aow = (const float*)d_in[7];
  const float* aob = (const float*)d_in[8];
  const float* Wn  = (const float*)d_in[9];
  const float* bnn = (const float*)d_in[10];
  const int* vrl   = (const int*)d_in[11];
  const int* gl    = (const int*)d_in[12];
  float* out = (float*)d_out;
  float* ws  = (float*)d_ws;
  int* icnt  = (int*)(ws + WS_CNT);
  int* ipair = (int*)(ws + WS_PAIR);

  k1a<<<dim3((kC1 + 255) / 256, kNDS), 256, 0, stream>>>(rep, Wv, Wr, ws + WS_PART);
  k1b<<<(kB * kC1 + 255) / 256, 256, 0, stream>>>(ws + WS_PART, bv, br, out, ws + WS_NODE);
  k0<<<1, 256, 0, stream>>>(vrl, icnt, ipair);
  k2<<<kV, 192, 0, stream>>>(ws + WS_NODE, vrl, aiw, aib, aow, aob, ws + WS_X);
  k3a<<<dim3(kR, kGC), 256, 0, stream>>>(ws + WS_X, icnt, ipair, gl, Wn, bnn,
                                         ws + WS_PM, ws + WS_PS, ws + WS_PI);
  k3b<<<(kV * kMR * kB + 255) / 256, 256, 0, stream>>>(vrl, gl, ws + WS_PM, ws + WS_PS,
                                                       ws + WS_PI, out);
  k4<<<kB, 256, 0, stream>>>(out);
}